// Round 11
// baseline (144.863 us; speedup 1.0000x reference)
//
#include <hip/hip_runtime.h>
#include <hip/hip_bf16.h>
#include <stdint.h>

#define S_LEN 4096
#define D_DIM 256
#define NBATCH 4
#define KVBLK 32
#define NHS 64    // half-steps in main schedule (each pair covers 64 tiles)
#define NSUP 32   // fallback super-steps

typedef unsigned short u16;
typedef float  f32x4  __attribute__((ext_vector_type(4)));
typedef __bf16 bf16x8 __attribute__((ext_vector_type(8)));
typedef __bf16 bf16x4 __attribute__((ext_vector_type(4)));
typedef short  s16x8  __attribute__((ext_vector_type(8)));
typedef short  s16x4  __attribute__((ext_vector_type(4)));

#define AS1 __attribute__((address_space(1)))
#define AS3 __attribute__((address_space(3)))

__device__ __forceinline__ f32x4 mfma16(bf16x8 a, bf16x8 b, f32x4 c) {
  return __builtin_amdgcn_mfma_f32_16x16x32_bf16(a, b, c, 0, 0, 0);
}

__device__ __forceinline__ s16x4 cvt4(float x, float y, float z, float w) {
  bf16x4 b;
  b[0] = (__bf16)x; b[1] = (__bf16)y; b[2] = (__bf16)z; b[3] = (__bf16)w;
  return __builtin_bit_cast(s16x4, b);
}

__device__ __forceinline__ void gload16(const void* g, void* l) {
  __builtin_amdgcn_global_load_lds((const AS1 unsigned int*)g,
                                   (AS3 unsigned int*)l, 16, 0, 0);
}

// ---------------------------------------------------------------------------
// R11 = R6's verified compute geometry (KVBLK=32, 2 q-slots/wave, 4-way
// split-K merge) + R9/R10's verified alternation schedule + image pre-pass.
//  4 groups x 2 waves. Pair P0 = {g0,g1}: keys [0,2048); P1 = {g2,g3}:
//  keys [2048,4096). Within a pair, R9 alternation (one group computes its
//  staged tile while the other DMAs its next tile image). Pairs are
//  ANTI-PHASED (cp = (gid&1)^(gid>>1)) so each SIMD has 1 computing +
//  1 staging wave every half-step.
// Tile images in d_ws (pre-pass, formulas = R6's verified staging):
//  K image [32 k][32 chunk]: chunk p of row k = K[k][8*(p^(k&7)) .. +8]
//  V image [256 d][4 chunk]: chunk c of row d = cols [8*(c^s_d) .. +8),
//    s_d = ((d>>4)^d)&3;  col -> k:  k = 16*(ii>>2) + 4*(col>>3) + (ii&3)
// ---------------------------------------------------------------------------

__global__ void build_kimg32(const float* __restrict__ K, u16* __restrict__ img) {
  const int wg  = blockIdx.x;              // (b*128 + T), 512 WGs
  const int tid = threadIdx.x;
  const float* src = K + (size_t)wg * KVBLK * D_DIM;
  u16*         dst = img + (size_t)wg * 8192;
  #pragma unroll
  for (int i = 0; i < 4; ++i) {
    const int idx = i * 256 + tid;         // 1024 chunks of 16B
    const int k = idx >> 5, p = idx & 31;
    const int q = p ^ (k & 7);
    const float* s = src + k * 256 + q * 8;
    float4 f0 = *reinterpret_cast<const float4*>(s);
    float4 f1 = *reinterpret_cast<const float4*>(s + 4);
    s16x8 v = __builtin_shufflevector(cvt4(f0.x, f0.y, f0.z, f0.w),
                                      cvt4(f1.x, f1.y, f1.z, f1.w),
                                      0, 1, 2, 3, 4, 5, 6, 7);
    *reinterpret_cast<s16x8*>(dst + k * 256 + p * 8) = v;
  }
}

__global__ void build_vimg32(const float* __restrict__ V, u16* __restrict__ img) {
  __shared__ u16 lds[KVBLK * 264];         // V tile bf16, row stride 264 u16
  const int wg  = blockIdx.x;              // (b*128 + T)
  const int tid = threadIdx.x;
  const float* src = V + (size_t)wg * KVBLK * D_DIM;
  u16*         dst = img + (size_t)wg * 8192;
  #pragma unroll
  for (int i = 0; i < 4; ++i) {
    const int idx = i * 256 + tid;         // 1024 chunks of 8 elems
    const int k = idx >> 5, q = idx & 31;
    const float* s = src + k * 256 + q * 8;
    float4 f0 = *reinterpret_cast<const float4*>(s);
    float4 f1 = *reinterpret_cast<const float4*>(s + 4);
    s16x8 v = __builtin_shufflevector(cvt4(f0.x, f0.y, f0.z, f0.w),
                                      cvt4(f1.x, f1.y, f1.z, f1.w),
                                      0, 1, 2, 3, 4, 5, 6, 7);
    *reinterpret_cast<s16x8*>(&lds[k * 264 + q * 8]) = v;
  }
  __syncthreads();
  const int d = tid;                        // one output row per thread
  const int s = ((d >> 4) ^ d) & 3;
  #pragma unroll
  for (int c = 0; c < 4; ++c) {
    const int gp = c ^ s;                   // col chunk held at position c
    s16x8 o;
    #pragma unroll
    for (int ii = 0; ii < 8; ++ii) {
      const int k = 16 * (ii >> 2) + 4 * gp + (ii & 3);
      o[ii] = (short)lds[k * 264 + d];
    }
    *reinterpret_cast<s16x8*>(dst + d * 32 + c * 8) = o;
  }
}

// ---- compute one staged 32-key tile, 2 q-slots (R6 verbatim, verified) ----
__device__ __forceinline__
void compute_tile2(const char* KsB, const char* VtB,
                   const bf16x8 (&qf)[2][8], f32x4 (&acc)[2][16],
                   float (&m_run)[2], float (&l_run)[2], int g, int h)
{
  const f32x4 fz = {0.f, 0.f, 0.f, 0.f};

  f32x4 st[2][2];
  st[0][0] = fz; st[0][1] = fz; st[1][0] = fz; st[1][1] = fz;
  __builtin_amdgcn_s_setprio(1);
  #pragma unroll
  for (int t = 0; t < 2; ++t) {
    const int row = t * 16 + h;
    const int sw  = (row & 7) << 4;
    #pragma unroll
    for (int dc = 0; dc < 8; ++dc) {
      s16x8 kf = *reinterpret_cast<const s16x8*>(KsB + row * 512 + ((dc * 64 + g * 16) ^ sw));
      st[0][t] = mfma16(__builtin_bit_cast(bf16x8, kf), qf[0][dc], st[0][t]);
      st[1][t] = mfma16(__builtin_bit_cast(bf16x8, kf), qf[1][dc], st[1][t]);
    }
  }
  __builtin_amdgcn_s_setprio(0);

  bf16x8 pa[2];
  #pragma unroll
  for (int qs = 0; qs < 2; ++qs) {
    float sv[8];
    #pragma unroll
    for (int t = 0; t < 2; ++t) {
      sv[t * 4 + 0] = st[qs][t][0]; sv[t * 4 + 1] = st[qs][t][1];
      sv[t * 4 + 2] = st[qs][t][2]; sv[t * 4 + 3] = st[qs][t][3];
    }
    float tmax = sv[0];
    #pragma unroll
    for (int i = 1; i < 8; ++i) tmax = fmaxf(tmax, sv[i]);
    tmax = fmaxf(tmax, __shfl_xor(tmax, 16));
    tmax = fmaxf(tmax, __shfl_xor(tmax, 32));

    if (!__all(tmax <= m_run[qs] + 8.0f)) {     // T13 defer-max
      const float mnew  = fmaxf(m_run[qs], tmax);
      const float alpha = __expf(m_run[qs] - mnew);
      l_run[qs] *= alpha;
      float af[4];
      #pragma unroll
      for (int r = 0; r < 4; ++r) af[r] = __shfl(alpha, g * 4 + r);
      #pragma unroll
      for (int dt = 0; dt < 16; ++dt) {
        acc[qs][dt][0] *= af[0]; acc[qs][dt][1] *= af[1];
        acc[qs][dt][2] *= af[2]; acc[qs][dt][3] *= af[3];
      }
      m_run[qs] = mnew;
    }

    float psum = 0.f;
    #pragma unroll
    for (int i = 0; i < 8; ++i) { sv[i] = __expf(sv[i] - m_run[qs]); psum += sv[i]; }
    psum += __shfl_xor(psum, 16);
    psum += __shfl_xor(psum, 32);
    l_run[qs] += psum;

    #pragma unroll
    for (int j = 0; j < 8; ++j) pa[qs][j] = (__bf16)sv[j];
  }

  __builtin_amdgcn_s_setprio(1);
  #pragma unroll
  for (int dt = 0; dt < 16; ++dt) {
    const int d = dt * 16 + h;
    s16x8 vf = *reinterpret_cast<const s16x8*>(VtB + d * 64 + ((16 * g) ^ (((dt ^ h) & 3) << 4)));
    acc[0][dt] = mfma16(pa[0], __builtin_bit_cast(bf16x8, vf), acc[0][dt]);
    acc[1][dt] = mfma16(pa[1], __builtin_bit_cast(bf16x8, vf), acc[1][dt]);
  }
  __builtin_amdgcn_s_setprio(0);
}

// ---- stage tile T: pure DMA of the 2x16KB images into this group's bufs ----
__device__ __forceinline__
void stage_img32(const u16* KimgB, const u16* VimgB, int T,
                 char* KsB, char* VtB, int gl)
{
  const char* ks = (const char*)(KimgB + (size_t)T * 8192) + gl * 16;
  const char* vs = (const char*)(VimgB + (size_t)T * 8192) + gl * 16;
  #pragma unroll
  for (int i = 0; i < 8; ++i) {
    gload16(ks + i * 2048, KsB + gl * 16 + i * 2048);
    gload16(vs + i * 2048, VtB + gl * 16 + i * 2048);
  }
}

template<bool USE_WS>
__global__ __launch_bounds__(512, 2)
void attn_fwd_kernel(const float* __restrict__ Qg, const void* __restrict__ Kp,
                     const void* __restrict__ Vp, float* __restrict__ Og)
{
  __shared__ __align__(16) char smem[133120];  // 4 x (16KB Ks + 16KB Vt) + 2KB ml

  const int wg   = blockIdx.x;                 // 256 WGs (1 per CU)
  const int swz  = (wg & 7) * 32 + (wg >> 3);  // bijective XCD swizzle
  const int b    = swz >> 6;
  const int qt   = swz & 63;
  const int tid  = threadIdx.x;
  const int wave = tid >> 6;                   // 0..7
  const int lane = tid & 63;
  const int g    = lane >> 4;
  const int h    = lane & 15;
  const int gid  = wave >> 1;                  // group 0..3
  const int wq   = wave & 1;                   // q-half within group
  const int ltid = tid & 127;                  // intra-group thread id

  // fallback V staging roles (per group): keys 4*kb..4*kb+3, d-chunk dcq
  const int kb  = ltid & 7;
  const int dcq = ltid >> 3;
  const int Xw  = 16 * (kb & 3) + 8 * (kb >> 2);

  char* KsB = smem + gid * 32768;
  char* VtB = KsB + 16384;
  float2* mlS = reinterpret_cast<float2*>(smem + 131072);

  const int qbase = qt * 64 + wq * 32;

  // Q fragments (B-operand of swapped QK^T), pre-scaled by 1/sqrt(256)
  bf16x8 qf[2][8];
  #pragma unroll
  for (int qs = 0; qs < 2; ++qs) {
    const float* qrow = Qg + ((size_t)b * S_LEN + qbase + qs * 16 + h) * D_DIM;
    #pragma unroll
    for (int dc = 0; dc < 8; ++dc) {
      float4 f0 = *reinterpret_cast<const float4*>(qrow + dc * 32 + g * 8);
      float4 f1 = *reinterpret_cast<const float4*>(qrow + dc * 32 + g * 8 + 4);
      bf16x8 q;
      q[0] = (__bf16)(f0.x * 0.0625f); q[1] = (__bf16)(f0.y * 0.0625f);
      q[2] = (__bf16)(f0.z * 0.0625f); q[3] = (__bf16)(f0.w * 0.0625f);
      q[4] = (__bf16)(f1.x * 0.0625f); q[5] = (__bf16)(f1.y * 0.0625f);
      q[6] = (__bf16)(f1.z * 0.0625f); q[7] = (__bf16)(f1.w * 0.0625f);
      qf[qs][dc] = q;
    }
  }

  f32x4 acc[2][16];
  const f32x4 fz = {0.f, 0.f, 0.f, 0.f};
  #pragma unroll
  for (int qs = 0; qs < 2; ++qs)
    #pragma unroll
    for (int i = 0; i < 16; ++i) acc[qs][i] = fz;
  float m_run[2] = {-1e30f, -1e30f};
  float l_run[2] = {0.f, 0.f};

  if constexpr (USE_WS) {
    const u16* KimgB = (const u16*)Kp + (size_t)b * 128 * 8192;
    const u16* VimgB = (const u16*)Vp + (size_t)b * 128 * 8192;

    const int cp    = (gid & 1) ^ (gid >> 1);  // compute parity (anti-phased pairs)
    const int tbase = (gid >> 1) * 64;         // pair key range base (in tiles)

    // ---- prologue: cp==0 groups stage their first tile ----
    if (cp == 0) stage_img32(KimgB, VimgB, tbase, KsB, VtB, ltid);
    __syncthreads();

    // ---- main loop: 1 barrier per half-step ----
    for (int hs = 0; hs < NHS; ++hs) {
      if ((hs & 1) == cp)
        compute_tile2(KsB, VtB, qf, acc, m_run, l_run, g, h);
      else if (hs < NHS - 1)
        stage_img32(KimgB, VimgB, tbase + hs + 1, KsB, VtB, ltid);
      __syncthreads();
    }

  } else {
    // fallback (fp32 inputs, serial staging; R6 verbatim) — d_ws too small
    const float* Kf = (const float*)Kp + (size_t)b * S_LEN * D_DIM;
    const float* Vf = (const float*)Vp + (size_t)b * S_LEN * D_DIM;
    const int rk = ltid >> 2, ck = ltid & 3;
    for (int s = 0; s < NSUP; ++s) {
      const int tile = 4 * s + gid;
      __syncthreads();
      #pragma unroll
      for (int i = 0; i < 8; ++i) {
        const float* src = Kf + (size_t)(tile * KVBLK + rk) * D_DIM + ck * 64 + i * 8;
        float4 f0 = *reinterpret_cast<const float4*>(src);
        float4 f1 = *reinterpret_cast<const float4*>(src + 4);
        char* dst = KsB + rk * 512 + ((ck * 128 + i * 16) ^ ((rk & 7) << 4));
        *reinterpret_cast<s16x4*>(dst)     = cvt4(f0.x, f0.y, f0.z, f0.w);
        *reinterpret_cast<s16x4*>(dst + 8) = cvt4(f1.x, f1.y, f1.z, f1.w);
      }
      {
        s16x8 lo[4], hi[4];
        #pragma unroll
        for (int r = 0; r < 4; ++r) {
          const float* src = Vf + (size_t)(tile * KVBLK + kb * 4 + r) * D_DIM + dcq * 16;
          float4 f0 = *reinterpret_cast<const float4*>(src);
          float4 f1 = *reinterpret_cast<const float4*>(src + 4);
          float4 f2 = *reinterpret_cast<const float4*>(src + 8);
          float4 f3 = *reinterpret_cast<const float4*>(src + 12);
          lo[r] = __builtin_shufflevector(cvt4(f0.x, f0.y, f0.z, f0.w),
                                          cvt4(f1.x, f1.y, f1.z, f1.w), 0, 1, 2, 3, 4, 5, 6, 7);
          hi[r] = __builtin_shufflevector(cvt4(f2.x, f2.y, f2.z, f2.w),
                                          cvt4(f3.x, f3.y, f3.z, f3.w), 0, 1, 2, 3, 4, 5, 6, 7);
        }
        #pragma unroll
        for (int j = 0; j < 8; ++j) {
          s16x4 c0, c1;
          c0[0] = lo[0][j]; c0[1] = lo[1][j]; c0[2] = lo[2][j]; c0[3] = lo[3][j];
          c1[0] = hi[0][j]; c1[1] = hi[1][j]; c1[2] = hi[2][j]; c1[3] = hi[3][j];
          const int d0 = dcq * 16 + j;
          const int d1 = d0 + 8;
          *reinterpret_cast<s16x4*>(VtB + d0 * 64 + (Xw ^ ((((d0 >> 4) ^ d0) & 3) << 4))) = c0;
          *reinterpret_cast<s16x4*>(VtB + d1 * 64 + (Xw ^ ((((d1 >> 4) ^ d1) & 3) << 4))) = c1;
        }
      }
      __syncthreads();
      compute_tile2(KsB, VtB, qf, acc, m_run, l_run, g, h);
    }
  }

  // ---- 4-way split-K merge: 2 rounds through the dead tile buffers ----
  // (R6 verbatim, correctness-verified)
  __syncthreads();
  if (gid >= 2) {
    char* base = smem + ((gid - 2) * 2 + wq) * 32768 + lane * 512;
    #pragma unroll
    for (int qs = 0; qs < 2; ++qs)
      #pragma unroll
      for (int dt = 0; dt < 16; ++dt)
        *reinterpret_cast<f32x4*>(base + (((qs * 16 + dt) * 16) ^ ((lane & 7) << 4))) = acc[qs][dt];
    if (lane < 16) {
      float2 a; a.x = m_run[0]; a.y = l_run[0]; mlS[wave * 32 + lane]      = a;
      float2 c; c.x = m_run[1]; c.y = l_run[1]; mlS[wave * 32 + 16 + lane] = c;
    }
  }
  __syncthreads();
  if (gid < 2) {
    const int pw = (gid + 2) * 2 + wq;
    const char* base = smem + (gid * 2 + wq) * 32768 + lane * 512;
    #pragma unroll
    for (int qs = 0; qs < 2; ++qs) {
      const float2 mlB = mlS[pw * 32 + qs * 16 + h];
      const float mN = fmaxf(m_run[qs], mlB.x);
      const float sA = __expf(m_run[qs] - mN);
      const float sB = __expf(mlB.x - mN);
      l_run[qs] = l_run[qs] * sA + mlB.y * sB;
      m_run[qs] = mN;
      float aA[4], aB[4];
      #pragma unroll
      for (int r = 0; r < 4; ++r) { aA[r] = __shfl(sA, g * 4 + r); aB[r] = __shfl(sB, g * 4 + r); }
      #pragma unroll
      for (int dt = 0; dt < 16; ++dt) {
        f32x4 ab = *reinterpret_cast<const f32x4*>(base + (((qs * 16 + dt) * 16) ^ ((lane & 7) << 4)));
        acc[qs][dt][0] = acc[qs][dt][0] * aA[0] + ab[0] * aB[0];
        acc[qs][dt][1] = acc[qs][dt][1] * aA[1] + ab[1] * aB[1];
        acc[qs][dt][2] = acc[qs][dt][2] * aA[2] + ab[2] * aB[2];
        acc[qs][dt][3] = acc[qs][dt][3] * aA[3] + ab[3] * aB[3];
      }
    }
  }
  __syncthreads();
  if (gid == 1) {
    char* base = smem + wq * 32768 + lane * 512;
    #pragma unroll
    for (int qs = 0; qs < 2; ++qs)
      #pragma unroll
      for (int dt = 0; dt < 16; ++dt)
        *reinterpret_cast<f32x4*>(base + (((qs * 16 + dt) * 16) ^ ((lane & 7) << 4))) = acc[qs][dt];
    if (lane < 16) {
      float2 a; a.x = m_run[0]; a.y = l_run[0]; mlS[wave * 32 + lane]      = a;
      float2 c; c.x = m_run[1]; c.y = l_run[1]; mlS[wave * 32 + 16 + lane] = c;
    }
  }
  __syncthreads();
  if (gid == 0) {
    const int pw = 2 + wq;
    const char* base = smem + wq * 32768 + lane * 512;
    float* orow0 = Og + ((size_t)b * S_LEN + qbase) * D_DIM;
    #pragma unroll
    for (int qs = 0; qs < 2; ++qs) {
      const float2 mlB = mlS[pw * 32 + qs * 16 + h];
      const float mN = fmaxf(m_run[qs], mlB.x);
      const float sA = __expf(m_run[qs] - mN);
      const float sB = __expf(mlB.x - mN);
      const float lN = l_run[qs] * sA + mlB.y * sB;
      float aA[4], aB[4], inv[4];
      #pragma unroll
      for (int r = 0; r < 4; ++r) {
        aA[r]  = __shfl(sA, g * 4 + r);
        aB[r]  = __shfl(sB, g * 4 + r);
        inv[r] = 1.f / __shfl(lN, g * 4 + r);
      }
      #pragma unroll
      for (int dt = 0; dt < 16; ++dt) {
        f32x4 ab = *reinterpret_cast<const f32x4*>(base + (((qs * 16 + dt) * 16) ^ ((lane & 7) << 4)));
        #pragma unroll
        for (int r = 0; r < 4; ++r) {
          orow0[(size_t)(qs * 16 + g * 4 + r) * D_DIM + dt * 16 + h] =
              (acc[qs][dt][r] * aA[r] + ab[r] * aB[r]) * inv[r];
        }
      }
    }
  }
}

extern "C" void kernel_launch(void* const* d_in, const int* in_sizes, int n_in,
                              void* d_out, int out_size, void* d_ws, size_t ws_size,
                              hipStream_t stream)
{
  const float* Q = (const float*)d_in[0];
  const float* K = (const float*)d_in[1];
  const float* V = (const float*)d_in[2];
  float* O = (float*)d_out;

  const size_t nelem = (size_t)NBATCH * S_LEN * D_DIM;   // 4,194,304
  const size_t need  = 2 * nelem * sizeof(u16);          // 16 MiB

  if (ws_size >= need) {
    u16* Kimg = (u16*)d_ws;                 // 4 batches x 128 tiles x 8192 u16
    u16* Vimg = Kimg + nelem;
    build_kimg32<<<512, 256, 0, stream>>>(K, Kimg);
    build_vimg32<<<512, 256, 0, stream>>>(V, Vimg);
    attn_fwd_kernel<true><<<256, 512, 0, stream>>>(Q, (const void*)Kimg, (const void*)Vimg, O);
  } else {
    attn_fwd_kernel<false><<<256, 512, 0, stream>>>(Q, (const void*)K, (const void*)V, O);
  }
}